// Round 1
// baseline (690.317 us; speedup 1.0000x reference)
//
#include <hip/hip_runtime.h>
#include <hip/hip_bf16.h>
#include <math.h>

#define BB 4
#define CC 64
#define HH 128
#define WW 128
#define DD 128
#define NN 64
#define HF 128
#define WF 65
#define LL 8320
#define TSEG 64
#define NSEG 130
#define PI2f 6.283185307179586f

// ---------------- K0: weight transposes (WcatT[k][o] 128x256, WoT[d][e] 128x128) ----
__global__ void k0_transpose(const float* __restrict__ Wx, const float* __restrict__ Wb,
                             const float* __restrict__ Wc, const float* __restrict__ Wout,
                             float* __restrict__ WcatT, float* __restrict__ WoT) {
  int idx = blockIdx.x * 256 + threadIdx.x;
  if (idx < 128 * 256) {
    int k = idx >> 8, o = idx & 255;
    float v;
    if (o < 128)      v = Wx[o * 128 + k];
    else if (o < 192) v = Wb[(o - 128) * 128 + k];
    else              v = Wc[(o - 192) * 128 + k];
    WcatT[k * 256 + o] = v;
  }
  if (idx < 128 * 128) {
    int d = idx >> 7, e = idx & 127;
    WoT[d * 128 + e] = Wout[e * 128 + d];
  }
}

// ---------------- K1: real 128-pt DFT along W for each (b,c,h) row; ortho 1/128 ----
__global__ __launch_bounds__(256) void k1_rfft_rows(const float* __restrict__ x,
                                                    float* __restrict__ T1) {
  __shared__ float xr[4][128];
  __shared__ float2 tw[128];
  int tid = threadIdx.x;
  if (tid < 128) {
    float sv, cv;
    sincosf(PI2f * (float)tid * (1.f / 128.f), &sv, &cv);
    tw[tid] = make_float2(cv, sv);
  }
  int wid = tid >> 6, lane = tid & 63;
  int row = blockIdx.x * 4 + wid;  // (b*C+c)*H + h
  xr[wid][lane]      = x[row * 128 + lane];
  xr[wid][lane + 64] = x[row * 128 + lane + 64];
  __syncthreads();
  int k = lane;
  float re = 0.f, im = 0.f, re64 = 0.f;
  for (int w = 0; w < 128; w++) {
    float xv = xr[wid][w];
    float2 tt = tw[(k * w) & 127];
    re = fmaf(xv, tt.x, re);
    im = fmaf(xv, -tt.y, im);
    re64 += (w & 1) ? -xv : xv;
  }
  const float inv = 1.f / 128.f;
  float2* o = (float2*)T1 + row * 65;
  o[k] = make_float2(re * inv, im * inv);
  if (lane == 0) o[64] = make_float2(re64 * inv, 0.f);
}

// ---------------- K2: complex 128-pt DFT along H per (b,c,wf); writes u[b][l][d] ----
__global__ __launch_bounds__(128) void k2_fft_cols(const float* __restrict__ T1,
                                                   float* __restrict__ u) {
  __shared__ float2 col[128];
  __shared__ float2 tw[128];
  int tid = threadIdx.x;
  {
    float sv, cv;
    sincosf(PI2f * (float)tid * (1.f / 128.f), &sv, &cv);
    tw[tid] = make_float2(cv, sv);
  }
  int bc = blockIdx.x / 65, wf = blockIdx.x % 65;
  col[tid] = ((const float2*)T1)[(bc * 128 + tid) * 65 + wf];
  __syncthreads();
  float re = 0.f, im = 0.f;
  int hf = tid;
  for (int j = 0; j < 128; j++) {
    float2 F = col[j];
    float2 tt = tw[(hf * j) & 127];
    re += F.x * tt.x + F.y * tt.y;   // (Fx+iFy)*(c - i s)
    im += F.y * tt.x - F.x * tt.y;
  }
  int b = bc >> 6, c = bc & 63;
  float* urow = u + (b * LL + hf * 65 + wf) * 128;
  urow[c] = re;
  urow[64 + c] = im;
}

// ---------------- K3: fused LayerNorm + projections (xs/Bs/Cs/dt/dec) ---------------
__global__ __launch_bounds__(256) void k3_ln_proj(
    const float* __restrict__ u, const float* __restrict__ WcatT,
    const float* __restrict__ nw, const float* __restrict__ nb,
    const float* __restrict__ wdt, const float* __restrict__ dtbias,
    const float* __restrict__ Alog,
    float* __restrict__ xs, float* __restrict__ Bs, float* __restrict__ Cs,
    float* __restrict__ dtb, float* __restrict__ decb) {
  __shared__ __align__(16) float su[32 * 128];
  int tid = threadIdx.x;
  int b = blockIdx.x / 260, tile = blockIdx.x % 260;
  int l0 = tile * 32;
  const float* ug = u + (b * LL + l0) * 128;
#pragma unroll
  for (int i = 0; i < 16; i++) su[i * 256 + tid] = ug[i * 256 + tid];
  __syncthreads();
  // LayerNorm: 8 threads per token, 16 channels each
  int t = tid >> 3, j = tid & 7;
  float vals[16];
  float s = 0.f, s2 = 0.f;
#pragma unroll
  for (int i = 0; i < 16; i++) {
    float v = su[t * 128 + j + 8 * i];
    vals[i] = v; s += v; s2 += v * v;
  }
#pragma unroll
  for (int off = 1; off < 8; off <<= 1) {
    s += __shfl_xor(s, off, 64);
    s2 += __shfl_xor(s2, off, 64);
  }
  float mu = s * (1.f / 128.f);
  float var = s2 * (1.f / 128.f) - mu * mu;
  float rs = rsqrtf(var + 1e-5f);
  float raw = 0.f;
#pragma unroll
  for (int i = 0; i < 16; i++) {
    int d = j + 8 * i;
    float v = ((vals[i] - mu) * rs * nw[d] + nb[d]) * (1.f / 128.f);
    su[t * 128 + d] = v;
    raw = fmaf(v, wdt[d], raw);
  }
#pragma unroll
  for (int off = 1; off < 8; off <<= 1) raw += __shfl_xor(raw, off, 64);
  if (j == 0) {
    float z = raw + dtbias[0];
    float sp = fmaxf(z, 0.f) + log1pf(expf(-fabsf(z)));   // softplus, stable
    dtb[b * LL + l0 + t] = sp;
    decb[b * LL + l0 + t] = expf(-expf(Alog[0]) * sp);
  }
  __syncthreads();
  // GEMM: 32 tokens x 256 outputs, K=128
  int og = tid & 31, tg = tid >> 5;
  int o0 = og * 8, t0 = tg * 4;
  float acc[4][8];
#pragma unroll
  for (int i = 0; i < 4; i++)
#pragma unroll
    for (int jj = 0; jj < 8; jj++) acc[i][jj] = 0.f;
  const float4* W4 = (const float4*)WcatT;
  const float4* su4 = (const float4*)su;
  int wofs = o0 >> 2;
  for (int kq = 0; kq < 32; kq++) {
    float4 uu[4];
#pragma unroll
    for (int i = 0; i < 4; i++) uu[i] = su4[(t0 + i) * 32 + kq];
#pragma unroll
    for (int kk = 0; kk < 4; kk++) {
      int k = kq * 4 + kk;
      float4 w0 = W4[k * 64 + wofs];
      float4 w1 = W4[k * 64 + wofs + 1];
      float wv[8] = {w0.x, w0.y, w0.z, w0.w, w1.x, w1.y, w1.z, w1.w};
#pragma unroll
      for (int i = 0; i < 4; i++) {
        float uv = (kk == 0) ? uu[i].x : (kk == 1) ? uu[i].y : (kk == 2) ? uu[i].z : uu[i].w;
#pragma unroll
        for (int jj = 0; jj < 8; jj++) acc[i][jj] = fmaf(uv, wv[jj], acc[i][jj]);
      }
    }
  }
#pragma unroll
  for (int i = 0; i < 4; i++) {
    int base = b * LL + l0 + t0 + i;
    float4 v0 = make_float4(acc[i][0], acc[i][1], acc[i][2], acc[i][3]);
    float4 v1 = make_float4(acc[i][4], acc[i][5], acc[i][6], acc[i][7]);
    if (o0 < 128) {
      float4* p = (float4*)(xs + base * 128 + o0);
      p[0] = v0; p[1] = v1;
    } else if (o0 < 192) {
      float4* p = (float4*)(Bs + base * 64 + (o0 - 128));
      p[0] = v0; p[1] = v1;
    } else {
      float4* p = (float4*)(Cs + base * 64 + (o0 - 192));
      p[0] = v0; p[1] = v1;
    }
  }
}

// ---------------- K5a: segmented scan (64 tokens), local y + segment state ---------
__global__ __launch_bounds__(256) void k5a_scan_seg(
    const float* __restrict__ xs, const float* __restrict__ Bs, const float* __restrict__ Cs,
    const float* __restrict__ dtb, const float* __restrict__ decb,
    const float* __restrict__ Dskip,
    float* __restrict__ ybuf, float* __restrict__ Sseg, float* __restrict__ ssegb,
    float* __restrict__ cumg) {
  int tid = threadIdx.x;
  int gw = blockIdx.x * 4 + (tid >> 6);      // wave = (b, seg, d)
  int lane = tid & 63;                       // lane = n
  int b = gw / (NSEG * 128);
  int rem = gw - b * (NSEG * 128);
  int seg = rem >> 7;
  int d = rem & 127;
  int tokbase = b * LL + seg * TSEG;
  const float* px = xs + tokbase * 128 + d;
  const float* pB = Bs + tokbase * 64 + lane;
  const float* pC = Cs + tokbase * 64 + lane;
  const float* pdt = dtb + tokbase;
  const float* pdc = decb + tokbase;
  float* py = ybuf + tokbase * 128 + d;
  float dsk = Dskip[d];
  float h = 0.f, g = 1.f;
  bool cwrite = (d == 0) && (lane == 0);
  for (int t = 0; t < TSEG; t++) {
    float dec = pdc[t];
    float dtv = pdt[t];
    float xv = px[t * 128];
    float Bn = pB[t * 64];
    float Cn = pC[t * 64];
    g *= dec;
    h = fmaf(dec, h, dtv * xv * Bn);
    float p = h * Cn;
#pragma unroll
    for (int off = 32; off >= 1; off >>= 1) p += __shfl_xor(p, off, 64);
    if (lane == 0) py[t * 128] = fmaf(dsk, xv, p);
    if (cwrite) cumg[tokbase + t] = g;
  }
  Sseg[(seg * BB + b) * 8192 + d * 64 + lane] = h;
  if (cwrite) ssegb[seg * BB + b] = g;
}

// ---------------- K5b: segment-boundary state recurrence + h_last ------------------
__global__ void k5b_states(const float* __restrict__ h_prev, const float* __restrict__ Sseg,
                           const float* __restrict__ ssegb, float* __restrict__ Hp,
                           float* __restrict__ h_last) {
  int gid = blockIdx.x * 256 + threadIdx.x;   // (b*128+d)*64+n, 32768 total
  int b = gid >> 13;
  float h = h_prev[gid];
  for (int p = 0; p < NSEG; p++) {
    Hp[p * 32768 + gid] = h;                  // state at segment START
    h = fmaf(ssegb[p * 4 + b], h, Sseg[p * 32768 + gid]);
  }
  h_last[gid] = h;
}

// ---------------- K5c: inter-segment correction  y += cumg * (C . Hp) --------------
__global__ __launch_bounds__(256) void k5c_correct(
    const float* __restrict__ Cs, const float* __restrict__ Hp,
    const float* __restrict__ cumg, float* __restrict__ ybuf) {
  __shared__ __align__(16) float Ct[64 * 64];    // [n][t]
  __shared__ __align__(16) float Ht[64 * 132];   // [n][d] padded
  __shared__ float cg[64];
  int tid = threadIdx.x;
  int b = blockIdx.x / NSEG, seg = blockIdx.x % NSEG;
  int tokbase = b * LL + seg * 64;
  const float* Csrc = Cs + tokbase * 64;
#pragma unroll
  for (int i = 0; i < 16; i++) {
    int e = tid + i * 256;
    Ct[(e & 63) * 64 + (e >> 6)] = Csrc[e];
  }
  const float* Hsrc = Hp + seg * 32768 + b * 8192;
#pragma unroll
  for (int i = 0; i < 32; i++) {
    int e = tid + i * 256;
    Ht[(e & 63) * 132 + (e >> 6)] = Hsrc[e];
  }
  if (tid < 64) cg[tid] = cumg[tokbase + tid];
  __syncthreads();
  int og = tid & 15, tg = tid >> 4;
  int d0 = og * 8, t0 = tg * 4;
  float acc[4][8];
#pragma unroll
  for (int i = 0; i < 4; i++)
#pragma unroll
    for (int jj = 0; jj < 8; jj++) acc[i][jj] = 0.f;
  for (int n = 0; n < 64; n++) {
    float4 c4 = *(const float4*)&Ct[n * 64 + t0];
    float4 h0 = *(const float4*)&Ht[n * 132 + d0];
    float4 h1 = *(const float4*)&Ht[n * 132 + d0 + 4];
    float cv[4] = {c4.x, c4.y, c4.z, c4.w};
    float hv[8] = {h0.x, h0.y, h0.z, h0.w, h1.x, h1.y, h1.z, h1.w};
#pragma unroll
    for (int i = 0; i < 4; i++)
#pragma unroll
      for (int jj = 0; jj < 8; jj++) acc[i][jj] = fmaf(cv[i], hv[jj], acc[i][jj]);
  }
#pragma unroll
  for (int i = 0; i < 4; i++) {
    float sc = cg[t0 + i];
    float* yp = ybuf + (tokbase + t0 + i) * 128 + d0;
    float4 y0 = *(float4*)yp;
    float4 y1 = *(float4*)(yp + 4);
    y0.x = fmaf(sc, acc[i][0], y0.x); y0.y = fmaf(sc, acc[i][1], y0.y);
    y0.z = fmaf(sc, acc[i][2], y0.z); y0.w = fmaf(sc, acc[i][3], y0.w);
    y1.x = fmaf(sc, acc[i][4], y1.x); y1.y = fmaf(sc, acc[i][5], y1.y);
    y1.z = fmaf(sc, acc[i][6], y1.z); y1.w = fmaf(sc, acc[i][7], y1.w);
    *(float4*)yp = y0; *(float4*)(yp + 4) = y1;
  }
}

// ---------------- K6: output projection -> freq domain (x128), complex pack --------
__global__ __launch_bounds__(256) void k6_outproj(
    const float* __restrict__ ybuf, const float* __restrict__ WoT,
    float* __restrict__ T2) {
  __shared__ __align__(16) float sy[32 * 128];
  int tid = threadIdx.x;
  int b = blockIdx.x / 260, tile = blockIdx.x % 260;
  int l0 = tile * 32;
  const float* yg = ybuf + (b * LL + l0) * 128;
#pragma unroll
  for (int i = 0; i < 16; i++) sy[i * 256 + tid] = yg[i * 256 + tid];
  __syncthreads();
  int og = tid & 15, tg = tid >> 4;
  int e0 = og * 8, t0 = tg * 2;
  float acc[2][8];
#pragma unroll
  for (int i = 0; i < 2; i++)
#pragma unroll
    for (int jj = 0; jj < 8; jj++) acc[i][jj] = 0.f;
  const float4* W4 = (const float4*)WoT;
  const float4* sy4 = (const float4*)sy;
  int wofs = e0 >> 2;
  for (int kq = 0; kq < 32; kq++) {
    float4 uu[2];
    uu[0] = sy4[t0 * 32 + kq];
    uu[1] = sy4[(t0 + 1) * 32 + kq];
#pragma unroll
    for (int kk = 0; kk < 4; kk++) {
      int k = kq * 4 + kk;
      float4 w0 = W4[k * 32 + wofs];
      float4 w1 = W4[k * 32 + wofs + 1];
      float wv[8] = {w0.x, w0.y, w0.z, w0.w, w1.x, w1.y, w1.z, w1.w};
#pragma unroll
      for (int i = 0; i < 2; i++) {
        float uv = (kk == 0) ? uu[i].x : (kk == 1) ? uu[i].y : (kk == 2) ? uu[i].z : uu[i].w;
#pragma unroll
        for (int jj = 0; jj < 8; jj++) acc[i][jj] = fmaf(uv, wv[jj], acc[i][jj]);
      }
    }
  }
#pragma unroll
  for (int i = 0; i < 2; i++) {
    int l = l0 + t0 + i;
#pragma unroll
    for (int jj = 0; jj < 8; jj++) {
      int e = e0 + jj;
      int c = e & 63;
      T2[((b * 64 + c) * LL + l) * 2 + (e >> 6)] = acc[i][jj] * 128.f;
    }
  }
}

// ---------------- K7: inverse complex 128-pt DFT along H ---------------------------
__global__ __launch_bounds__(128) void k7_ifft_cols(const float* __restrict__ T2,
                                                    float* __restrict__ TY) {
  __shared__ float2 col[128];
  __shared__ float2 tw[128];
  int tid = threadIdx.x;
  {
    float sv, cv;
    sincosf(PI2f * (float)tid * (1.f / 128.f), &sv, &cv);
    tw[tid] = make_float2(cv, sv);
  }
  int bc = blockIdx.x / 65, wf = blockIdx.x % 65;
  col[tid] = ((const float2*)T2)[bc * LL + tid * 65 + wf];
  __syncthreads();
  float re = 0.f, im = 0.f;
  int h = tid;
  for (int j = 0; j < 128; j++) {
    float2 F = col[j];
    float2 tt = tw[(h * j) & 127];
    re += F.x * tt.x - F.y * tt.y;   // (Fx+iFy)*(c + i s)
    im += F.x * tt.y + F.y * tt.x;
  }
  ((float2*)TY)[(bc * 128 + h) * 65 + wf] = make_float2(re, im);
}

// ---------------- K8: inverse real DFT along W (Hermitian), ortho 1/128 ------------
__global__ __launch_bounds__(128) void k8_irfft_rows(const float* __restrict__ TY,
                                                     float* __restrict__ out) {
  __shared__ float2 Z[65];
  __shared__ float2 tw[128];
  int tid = threadIdx.x;
  {
    float sv, cv;
    sincosf(PI2f * (float)tid * (1.f / 128.f), &sv, &cv);
    tw[tid] = make_float2(cv, sv);
  }
  int row = blockIdx.x;  // (b*C+c)*H + h
  if (tid < 65) Z[tid] = ((const float2*)TY)[row * 65 + tid];
  __syncthreads();
  int w = tid;
  float acc = Z[0].x + ((w & 1) ? -Z[64].x : Z[64].x);
  for (int k = 1; k < 64; k++) {
    float2 tt = tw[(k * w) & 127];
    acc += 2.f * (Z[k].x * tt.x - Z[k].y * tt.y);
  }
  out[row * 128 + w] = acc * (1.f / 128.f);
}

extern "C" void kernel_launch(void* const* d_in, const int* in_sizes, int n_in,
                              void* d_out, int out_size, void* d_ws, size_t ws_size,
                              hipStream_t stream) {
  const float* x      = (const float*)d_in[0];
  const float* h_prev = (const float*)d_in[1];
  const float* nw     = (const float*)d_in[2];
  const float* nb     = (const float*)d_in[3];
  const float* Wx     = (const float*)d_in[4];
  const float* Wb     = (const float*)d_in[5];
  const float* Wc     = (const float*)d_in[6];
  const float* wdt    = (const float*)d_in[7];
  const float* dtbias = (const float*)d_in[8];
  const float* Alog   = (const float*)d_in[9];
  const float* Dskip  = (const float*)d_in[10];
  const float* Wout   = (const float*)d_in[11];
  float* out = (float*)d_out;

  float* ws = (float*)d_ws;
  const size_t SZ_BIG = 4259840;  // B*L*D
  const size_t SZ_BN  = 2129920;  // B*L*N
  float* R1    = ws;              // T1 (rfft rows) then T2 (freq_out)
  float* R2    = R1 + SZ_BIG;     // u, then Sseg
  float* R3    = R2 + SZ_BIG;     // xs, then Hp
  float* R4    = R3 + SZ_BIG;     // ybuf, then TY (ifft-cols out)
  float* Bs    = R4 + SZ_BIG;
  float* Cs    = Bs + SZ_BN;
  float* dtb   = Cs + SZ_BN;      // 33280
  float* decb  = dtb + 33280;     // 33280
  float* cumg  = decb + 33280;    // 33280
  float* ssegb = cumg + 33280;    // 520
  float* WcatT = ssegb + 520;     // 32768
  float* WoT   = WcatT + 32768;   // 16384

  hipLaunchKernelGGL(k0_transpose, dim3(128), dim3(256), 0, stream, Wx, Wb, Wc, Wout, WcatT, WoT);
  hipLaunchKernelGGL(k1_rfft_rows, dim3(8192), dim3(256), 0, stream, x, R1);
  hipLaunchKernelGGL(k2_fft_cols, dim3(16640), dim3(128), 0, stream, R1, R2);
  hipLaunchKernelGGL(k3_ln_proj, dim3(1040), dim3(256), 0, stream,
                     R2, WcatT, nw, nb, wdt, dtbias, Alog, R3, Bs, Cs, dtb, decb);
  hipLaunchKernelGGL(k5a_scan_seg, dim3(16640), dim3(256), 0, stream,
                     R3, Bs, Cs, dtb, decb, Dskip, R4, R2 /*Sseg*/, ssegb, cumg);
  hipLaunchKernelGGL(k5b_states, dim3(128), dim3(256), 0, stream,
                     h_prev, R2, ssegb, R3 /*Hp*/, out + 4194304);
  hipLaunchKernelGGL(k5c_correct, dim3(520), dim3(256), 0, stream, Cs, R3, cumg, R4);
  hipLaunchKernelGGL(k6_outproj, dim3(1040), dim3(256), 0, stream, R4, WoT, R1 /*T2*/);
  hipLaunchKernelGGL(k7_ifft_cols, dim3(16640), dim3(128), 0, stream, R1, R4 /*TY*/);
  hipLaunchKernelGGL(k8_irfft_rows, dim3(32768), dim3(128), 0, stream, R4, out);
}

// Round 2
// 418.918 us; speedup vs baseline: 1.6479x; 1.6479x over previous
//
#include <hip/hip_runtime.h>
#include <hip/hip_bf16.h>
#include <math.h>

#define BB 4
#define CC 64
#define HH 128
#define WW 128
#define DD 128
#define NN 64
#define HF 128
#define WF 65
#define LL 8320
#define TSEG 64
#define NSEG 130
#define PI2f 6.283185307179586f

// ---------------- K0: weight transposes (WcatT[k][o] 128x256, WoT[d][e] 128x128) ----
__global__ void k0_transpose(const float* __restrict__ Wx, const float* __restrict__ Wb,
                             const float* __restrict__ Wc, const float* __restrict__ Wout,
                             float* __restrict__ WcatT, float* __restrict__ WoT) {
  int idx = blockIdx.x * 256 + threadIdx.x;
  if (idx < 128 * 256) {
    int k = idx >> 8, o = idx & 255;
    float v;
    if (o < 128)      v = Wx[o * 128 + k];
    else if (o < 192) v = Wb[(o - 128) * 128 + k];
    else              v = Wc[(o - 192) * 128 + k];
    WcatT[k * 256 + o] = v;
  }
  if (idx < 128 * 128) {
    int d = idx >> 7, e = idx & 127;
    WoT[d * 128 + e] = Wout[e * 128 + d];
  }
}

// ---------------- K1: real 128-pt DFT along W for each (b,c,h) row; ortho 1/128 ----
__global__ __launch_bounds__(256) void k1_rfft_rows(const float* __restrict__ x,
                                                    float* __restrict__ T1) {
  __shared__ float xr[4][128];
  __shared__ float2 tw[128];
  int tid = threadIdx.x;
  if (tid < 128) {
    float sv, cv;
    sincosf(PI2f * (float)tid * (1.f / 128.f), &sv, &cv);
    tw[tid] = make_float2(cv, sv);
  }
  int wid = tid >> 6, lane = tid & 63;
  int row = blockIdx.x * 4 + wid;  // (b*C+c)*H + h
  xr[wid][lane]      = x[row * 128 + lane];
  xr[wid][lane + 64] = x[row * 128 + lane + 64];
  __syncthreads();
  int k = lane;
  float re = 0.f, im = 0.f, re64 = 0.f;
  for (int w = 0; w < 128; w++) {
    float xv = xr[wid][w];
    float2 tt = tw[(k * w) & 127];
    re = fmaf(xv, tt.x, re);
    im = fmaf(xv, -tt.y, im);
    re64 += (w & 1) ? -xv : xv;
  }
  const float inv = 1.f / 128.f;
  float2* o = (float2*)T1 + row * 65;
  o[k] = make_float2(re * inv, im * inv);
  if (lane == 0) o[64] = make_float2(re64 * inv, 0.f);
}

// ---------------- K2: complex 128-pt DFT along H per (b,c,wf); writes u[b][l][d] ----
__global__ __launch_bounds__(128) void k2_fft_cols(const float* __restrict__ T1,
                                                   float* __restrict__ u) {
  __shared__ float2 col[128];
  __shared__ float2 tw[128];
  int tid = threadIdx.x;
  {
    float sv, cv;
    sincosf(PI2f * (float)tid * (1.f / 128.f), &sv, &cv);
    tw[tid] = make_float2(cv, sv);
  }
  int bc = blockIdx.x / 65, wf = blockIdx.x % 65;
  col[tid] = ((const float2*)T1)[(bc * 128 + tid) * 65 + wf];
  __syncthreads();
  float re = 0.f, im = 0.f;
  int hf = tid;
  for (int j = 0; j < 128; j++) {
    float2 F = col[j];
    float2 tt = tw[(hf * j) & 127];
    re += F.x * tt.x + F.y * tt.y;   // (Fx+iFy)*(c - i s)
    im += F.y * tt.x - F.x * tt.y;
  }
  int b = bc >> 6, c = bc & 63;
  float* urow = u + (b * LL + hf * 65 + wf) * 128;
  urow[c] = re;
  urow[64 + c] = im;
}

// ---------------- K3: fused LayerNorm + projections (xs/Bs/Cs/dt) -------------------
__global__ __launch_bounds__(256) void k3_ln_proj(
    const float* __restrict__ u, const float* __restrict__ WcatT,
    const float* __restrict__ nw, const float* __restrict__ nb,
    const float* __restrict__ wdt, const float* __restrict__ dtbias,
    float* __restrict__ xs, float* __restrict__ Bs, float* __restrict__ Cs,
    float* __restrict__ dtb) {
  __shared__ __align__(16) float su[32 * 128];
  int tid = threadIdx.x;
  int b = blockIdx.x / 260, tile = blockIdx.x % 260;
  int l0 = tile * 32;
  const float* ug = u + (b * LL + l0) * 128;
#pragma unroll
  for (int i = 0; i < 16; i++) su[i * 256 + tid] = ug[i * 256 + tid];
  __syncthreads();
  // LayerNorm: 8 threads per token, 16 channels each
  int t = tid >> 3, j = tid & 7;
  float vals[16];
  float s = 0.f, s2 = 0.f;
#pragma unroll
  for (int i = 0; i < 16; i++) {
    float v = su[t * 128 + j + 8 * i];
    vals[i] = v; s += v; s2 += v * v;
  }
#pragma unroll
  for (int off = 1; off < 8; off <<= 1) {
    s += __shfl_xor(s, off, 64);
    s2 += __shfl_xor(s2, off, 64);
  }
  float mu = s * (1.f / 128.f);
  float var = s2 * (1.f / 128.f) - mu * mu;
  float rs = rsqrtf(var + 1e-5f);
  float raw = 0.f;
#pragma unroll
  for (int i = 0; i < 16; i++) {
    int d = j + 8 * i;
    float v = ((vals[i] - mu) * rs * nw[d] + nb[d]) * (1.f / 128.f);
    su[t * 128 + d] = v;
    raw = fmaf(v, wdt[d], raw);
  }
#pragma unroll
  for (int off = 1; off < 8; off <<= 1) raw += __shfl_xor(raw, off, 64);
  if (j == 0) {
    float z = raw + dtbias[0];
    float sp = fmaxf(z, 0.f) + log1pf(expf(-fabsf(z)));   // softplus, stable
    dtb[b * LL + l0 + t] = sp;
  }
  __syncthreads();
  // GEMM: 32 tokens x 256 outputs, K=128
  int og = tid & 31, tg = tid >> 5;
  int o0 = og * 8, t0 = tg * 4;
  float acc[4][8];
#pragma unroll
  for (int i = 0; i < 4; i++)
#pragma unroll
    for (int jj = 0; jj < 8; jj++) acc[i][jj] = 0.f;
  const float4* W4 = (const float4*)WcatT;
  const float4* su4 = (const float4*)su;
  int wofs = o0 >> 2;
  for (int kq = 0; kq < 32; kq++) {
    float4 uu[4];
#pragma unroll
    for (int i = 0; i < 4; i++) uu[i] = su4[(t0 + i) * 32 + kq];
#pragma unroll
    for (int kk = 0; kk < 4; kk++) {
      int k = kq * 4 + kk;
      float4 w0 = W4[k * 64 + wofs];
      float4 w1 = W4[k * 64 + wofs + 1];
      float wv[8] = {w0.x, w0.y, w0.z, w0.w, w1.x, w1.y, w1.z, w1.w};
#pragma unroll
      for (int i = 0; i < 4; i++) {
        float uv = (kk == 0) ? uu[i].x : (kk == 1) ? uu[i].y : (kk == 2) ? uu[i].z : uu[i].w;
#pragma unroll
        for (int jj = 0; jj < 8; jj++) acc[i][jj] = fmaf(uv, wv[jj], acc[i][jj]);
      }
    }
  }
#pragma unroll
  for (int i = 0; i < 4; i++) {
    int base = b * LL + l0 + t0 + i;
    float4 v0 = make_float4(acc[i][0], acc[i][1], acc[i][2], acc[i][3]);
    float4 v1 = make_float4(acc[i][4], acc[i][5], acc[i][6], acc[i][7]);
    if (o0 < 128) {
      float4* p = (float4*)(xs + base * 128 + o0);
      p[0] = v0; p[1] = v1;
    } else if (o0 < 192) {
      float4* p = (float4*)(Bs + base * 64 + (o0 - 128));
      p[0] = v0; p[1] = v1;
    } else {
      float4* p = (float4*)(Cs + base * 64 + (o0 - 192));
      p[0] = v0; p[1] = v1;
    }
  }
}

// ---------------- K5: chunked-dual segment kernel (replaces serial scan) ------------
// Per (b,seg): G=C.B^T ; M[t,s]=exp(lc_t-lc_s)*dt_s*G (s<=t) ; Y=M.X + Dskip*X ;
// S[d,n]=sum_s exp(lc63-lc_s)*dt_s*X[s,d]*B[s,n] ; cumg_t=exp(lc_t) ; ssegb=exp(lc63)
__global__ __launch_bounds__(256) void k5_seg(
    const float* __restrict__ xs, const float* __restrict__ Bs, const float* __restrict__ Cs,
    const float* __restrict__ dtb, const float* __restrict__ Alog,
    const float* __restrict__ Dskip,
    float* __restrict__ ybuf, float* __restrict__ Sseg, float* __restrict__ ssegb,
    float* __restrict__ cumg) {
  __shared__ __align__(16) float sX[64 * 128];   // 32 KB
  __shared__ __align__(16) float sB[64 * 68];    // padded rows
  __shared__ __align__(16) float sCM[64 * 68];   // C, later M
  __shared__ float sdt[64], slc[64], sws[64];
  int tid = threadIdx.x;
  int b = blockIdx.x / NSEG, seg = blockIdx.x % NSEG;
  int tokbase = b * LL + seg * TSEG;
  // ---- stage
  const float4* xg = (const float4*)(xs + (size_t)tokbase * 128);
  float4* sX4 = (float4*)sX;
#pragma unroll
  for (int i = 0; i < 8; i++) sX4[i * 256 + tid] = xg[i * 256 + tid];
  const float4* bg = (const float4*)(Bs + (size_t)tokbase * 64);
  const float4* cg = (const float4*)(Cs + (size_t)tokbase * 64);
#pragma unroll
  for (int i = 0; i < 4; i++) {
    int e = i * 256 + tid;
    int t = e >> 4, n4 = e & 15;
    *(float4*)&sB[t * 68 + n4 * 4] = bg[e];
    *(float4*)&sCM[t * 68 + n4 * 4] = cg[e];
  }
  if (tid < 64) sdt[tid] = dtb[tokbase + tid];
  __syncthreads();
  // ---- wave 0: prefix-sum of log-decay, weights, global cumg/ssegb
  if (tid < 64) {
    float a = expf(Alog[0]);
    float v = -a * sdt[tid];
#pragma unroll
    for (int off = 1; off < 64; off <<= 1) {
      float o = __shfl_up(v, off, 64);
      if (tid >= off) v += o;
    }
    slc[tid] = v;
    float l63 = __shfl(v, 63, 64);
    sws[tid] = expf(l63 - v) * sdt[tid];
    cumg[tokbase + tid] = expf(v);
    if (tid == 63) ssegb[seg * BB + b] = expf(v);
  }
  __syncthreads();
  // ---- G = C . B^T   (thread: 4t x 4s tile)
  int t0 = (tid >> 4) * 4, s0 = (tid & 15) * 4;
  float g[4][4];
#pragma unroll
  for (int i = 0; i < 4; i++)
#pragma unroll
    for (int j = 0; j < 4; j++) g[i][j] = 0.f;
  for (int n4 = 0; n4 < 16; n4++) {
    float4 cr[4], br[4];
#pragma unroll
    for (int i = 0; i < 4; i++) cr[i] = *(const float4*)&sCM[(t0 + i) * 68 + n4 * 4];
#pragma unroll
    for (int j = 0; j < 4; j++) br[j] = *(const float4*)&sB[(s0 + j) * 68 + n4 * 4];
#pragma unroll
    for (int i = 0; i < 4; i++)
#pragma unroll
      for (int j = 0; j < 4; j++) {
        g[i][j] = fmaf(cr[i].x, br[j].x, g[i][j]);
        g[i][j] = fmaf(cr[i].y, br[j].y, g[i][j]);
        g[i][j] = fmaf(cr[i].z, br[j].z, g[i][j]);
        g[i][j] = fmaf(cr[i].w, br[j].w, g[i][j]);
      }
  }
  __syncthreads();     // everyone done reading C
  // ---- M into sCM (masked, scaled)
#pragma unroll
  for (int i = 0; i < 4; i++) {
    int t = t0 + i;
    float4 m;
    float lt = slc[t];
    m.x = (s0 + 0 <= t) ? expf(lt - slc[s0 + 0]) * sdt[s0 + 0] * g[i][0] : 0.f;
    m.y = (s0 + 1 <= t) ? expf(lt - slc[s0 + 1]) * sdt[s0 + 1] * g[i][1] : 0.f;
    m.z = (s0 + 2 <= t) ? expf(lt - slc[s0 + 2]) * sdt[s0 + 2] * g[i][2] : 0.f;
    m.w = (s0 + 3 <= t) ? expf(lt - slc[s0 + 3]) * sdt[s0 + 3] * g[i][3] : 0.f;
    *(float4*)&sCM[t * 68 + s0] = m;
  }
  __syncthreads();
  // ---- Y = M . X + Dskip*X   (thread: 4t x 8d tile)
  int d0 = (tid & 15) * 8;
  {
    float acc[4][8];
#pragma unroll
    for (int i = 0; i < 4; i++)
#pragma unroll
      for (int j = 0; j < 8; j++) acc[i][j] = 0.f;
    for (int s = 0; s < 64; s++) {
      float4 x0 = *(const float4*)&sX[s * 128 + d0];
      float4 x1 = *(const float4*)&sX[s * 128 + d0 + 4];
      float xv[8] = {x0.x, x0.y, x0.z, x0.w, x1.x, x1.y, x1.z, x1.w};
#pragma unroll
      for (int i = 0; i < 4; i++) {
        float m = sCM[(t0 + i) * 68 + s];
#pragma unroll
        for (int j = 0; j < 8; j++) acc[i][j] = fmaf(m, xv[j], acc[i][j]);
      }
    }
    float4 dk0 = *(const float4*)&Dskip[d0];
    float4 dk1 = *(const float4*)&Dskip[d0 + 4];
    float dk[8] = {dk0.x, dk0.y, dk0.z, dk0.w, dk1.x, dk1.y, dk1.z, dk1.w};
#pragma unroll
    for (int i = 0; i < 4; i++) {
      int t = t0 + i;
      float4 x0 = *(const float4*)&sX[t * 128 + d0];
      float4 x1 = *(const float4*)&sX[t * 128 + d0 + 4];
      float xv[8] = {x0.x, x0.y, x0.z, x0.w, x1.x, x1.y, x1.z, x1.w};
      float4 y0, y1;
      y0.x = fmaf(dk[0], xv[0], acc[i][0]); y0.y = fmaf(dk[1], xv[1], acc[i][1]);
      y0.z = fmaf(dk[2], xv[2], acc[i][2]); y0.w = fmaf(dk[3], xv[3], acc[i][3]);
      y1.x = fmaf(dk[4], xv[4], acc[i][4]); y1.y = fmaf(dk[5], xv[5], acc[i][5]);
      y1.z = fmaf(dk[6], xv[6], acc[i][6]); y1.w = fmaf(dk[7], xv[7], acc[i][7]);
      float* yp = ybuf + (size_t)(tokbase + t) * 128 + d0;
      *(float4*)yp = y0;
      *(float4*)(yp + 4) = y1;
    }
  }
  // ---- S[d,n] = sum_s sws[s] * X[s,d] * B[s,n]   (thread: 8d x 4n tile)
  {
    int dd0 = (tid >> 4) * 8, n0 = (tid & 15) * 4;
    float sacc[8][4];
#pragma unroll
    for (int k = 0; k < 8; k++)
#pragma unroll
      for (int j = 0; j < 4; j++) sacc[k][j] = 0.f;
    for (int s = 0; s < 64; s++) {
      float w = sws[s];
      float4 b4 = *(const float4*)&sB[s * 68 + n0];
      b4.x *= w; b4.y *= w; b4.z *= w; b4.w *= w;
      float4 x0 = *(const float4*)&sX[s * 128 + dd0];
      float4 x1 = *(const float4*)&sX[s * 128 + dd0 + 4];
      float xv[8] = {x0.x, x0.y, x0.z, x0.w, x1.x, x1.y, x1.z, x1.w};
#pragma unroll
      for (int k = 0; k < 8; k++) {
        sacc[k][0] = fmaf(xv[k], b4.x, sacc[k][0]);
        sacc[k][1] = fmaf(xv[k], b4.y, sacc[k][1]);
        sacc[k][2] = fmaf(xv[k], b4.z, sacc[k][2]);
        sacc[k][3] = fmaf(xv[k], b4.w, sacc[k][3]);
      }
    }
    float* Sp = Sseg + (size_t)seg * 32768 + (size_t)b * 8192;
#pragma unroll
    for (int k = 0; k < 8; k++)
      *(float4*)&Sp[(dd0 + k) * 64 + n0] =
          make_float4(sacc[k][0], sacc[k][1], sacc[k][2], sacc[k][3]);
  }
}

// ---------------- K5b: segment-boundary state recurrence + h_last ------------------
__global__ void k5b_states(const float* __restrict__ h_prev, const float* __restrict__ Sseg,
                           const float* __restrict__ ssegb, float* __restrict__ Hp,
                           float* __restrict__ h_last) {
  int gid = blockIdx.x * 256 + threadIdx.x;   // (b*128+d)*64+n, 32768 total
  int b = gid >> 13;
  float h = h_prev[gid];
  for (int p = 0; p < NSEG; p++) {
    Hp[p * 32768 + gid] = h;                  // state at segment START
    h = fmaf(ssegb[p * 4 + b], h, Sseg[p * 32768 + gid]);
  }
  h_last[gid] = h;
}

// ---------------- K5c: inter-segment correction  y += cumg * (C . Hp) --------------
__global__ __launch_bounds__(256) void k5c_correct(
    const float* __restrict__ Cs, const float* __restrict__ Hp,
    const float* __restrict__ cumg, float* __restrict__ ybuf) {
  __shared__ __align__(16) float Ct[64 * 64];    // [n][t]
  __shared__ __align__(16) float Ht[64 * 132];   // [n][d] padded
  __shared__ float cg[64];
  int tid = threadIdx.x;
  int b = blockIdx.x / NSEG, seg = blockIdx.x % NSEG;
  int tokbase = b * LL + seg * 64;
  const float* Csrc = Cs + tokbase * 64;
#pragma unroll
  for (int i = 0; i < 16; i++) {
    int e = tid + i * 256;
    Ct[(e & 63) * 64 + (e >> 6)] = Csrc[e];
  }
  const float* Hsrc = Hp + seg * 32768 + b * 8192;
#pragma unroll
  for (int i = 0; i < 32; i++) {
    int e = tid + i * 256;
    Ht[(e & 63) * 132 + (e >> 6)] = Hsrc[e];
  }
  if (tid < 64) cg[tid] = cumg[tokbase + tid];
  __syncthreads();
  int og = tid & 15, tg = tid >> 4;
  int d0 = og * 8, t0 = tg * 4;
  float acc[4][8];
#pragma unroll
  for (int i = 0; i < 4; i++)
#pragma unroll
    for (int jj = 0; jj < 8; jj++) acc[i][jj] = 0.f;
  for (int n = 0; n < 64; n++) {
    float4 c4 = *(const float4*)&Ct[n * 64 + t0];
    float4 h0 = *(const float4*)&Ht[n * 132 + d0];
    float4 h1 = *(const float4*)&Ht[n * 132 + d0 + 4];
    float cv[4] = {c4.x, c4.y, c4.z, c4.w};
    float hv[8] = {h0.x, h0.y, h0.z, h0.w, h1.x, h1.y, h1.z, h1.w};
#pragma unroll
    for (int i = 0; i < 4; i++)
#pragma unroll
      for (int jj = 0; jj < 8; jj++) acc[i][jj] = fmaf(cv[i], hv[jj], acc[i][jj]);
  }
#pragma unroll
  for (int i = 0; i < 4; i++) {
    float sc = cg[t0 + i];
    float* yp = ybuf + (tokbase + t0 + i) * 128 + d0;
    float4 y0 = *(float4*)yp;
    float4 y1 = *(float4*)(yp + 4);
    y0.x = fmaf(sc, acc[i][0], y0.x); y0.y = fmaf(sc, acc[i][1], y0.y);
    y0.z = fmaf(sc, acc[i][2], y0.z); y0.w = fmaf(sc, acc[i][3], y0.w);
    y1.x = fmaf(sc, acc[i][4], y1.x); y1.y = fmaf(sc, acc[i][5], y1.y);
    y1.z = fmaf(sc, acc[i][6], y1.z); y1.w = fmaf(sc, acc[i][7], y1.w);
    *(float4*)yp = y0; *(float4*)(yp + 4) = y1;
  }
}

// ---------------- K6: output projection -> freq domain (x128), complex pack --------
__global__ __launch_bounds__(256) void k6_outproj(
    const float* __restrict__ ybuf, const float* __restrict__ WoT,
    float* __restrict__ T2) {
  __shared__ __align__(16) float sy[32 * 128];
  int tid = threadIdx.x;
  int b = blockIdx.x / 260, tile = blockIdx.x % 260;
  int l0 = tile * 32;
  const float* yg = ybuf + (b * LL + l0) * 128;
#pragma unroll
  for (int i = 0; i < 16; i++) sy[i * 256 + tid] = yg[i * 256 + tid];
  __syncthreads();
  int og = tid & 15, tg = tid >> 4;
  int e0 = og * 8, t0 = tg * 2;
  float acc[2][8];
#pragma unroll
  for (int i = 0; i < 2; i++)
#pragma unroll
    for (int jj = 0; jj < 8; jj++) acc[i][jj] = 0.f;
  const float4* W4 = (const float4*)WoT;
  const float4* sy4 = (const float4*)sy;
  int wofs = e0 >> 2;
  for (int kq = 0; kq < 32; kq++) {
    float4 uu[2];
    uu[0] = sy4[t0 * 32 + kq];
    uu[1] = sy4[(t0 + 1) * 32 + kq];
#pragma unroll
    for (int kk = 0; kk < 4; kk++) {
      int k = kq * 4 + kk;
      float4 w0 = W4[k * 32 + wofs];
      float4 w1 = W4[k * 32 + wofs + 1];
      float wv[8] = {w0.x, w0.y, w0.z, w0.w, w1.x, w1.y, w1.z, w1.w};
#pragma unroll
      for (int i = 0; i < 2; i++) {
        float uv = (kk == 0) ? uu[i].x : (kk == 1) ? uu[i].y : (kk == 2) ? uu[i].z : uu[i].w;
#pragma unroll
        for (int jj = 0; jj < 8; jj++) acc[i][jj] = fmaf(uv, wv[jj], acc[i][jj]);
      }
    }
  }
#pragma unroll
  for (int i = 0; i < 2; i++) {
    int l = l0 + t0 + i;
#pragma unroll
    for (int jj = 0; jj < 8; jj++) {
      int e = e0 + jj;
      int c = e & 63;
      T2[((b * 64 + c) * LL + l) * 2 + (e >> 6)] = acc[i][jj] * 128.f;
    }
  }
}

// ---------------- K7: inverse complex 128-pt DFT along H ---------------------------
__global__ __launch_bounds__(128) void k7_ifft_cols(const float* __restrict__ T2,
                                                    float* __restrict__ TY) {
  __shared__ float2 col[128];
  __shared__ float2 tw[128];
  int tid = threadIdx.x;
  {
    float sv, cv;
    sincosf(PI2f * (float)tid * (1.f / 128.f), &sv, &cv);
    tw[tid] = make_float2(cv, sv);
  }
  int bc = blockIdx.x / 65, wf = blockIdx.x % 65;
  col[tid] = ((const float2*)T2)[bc * LL + tid * 65 + wf];
  __syncthreads();
  float re = 0.f, im = 0.f;
  int h = tid;
  for (int j = 0; j < 128; j++) {
    float2 F = col[j];
    float2 tt = tw[(h * j) & 127];
    re += F.x * tt.x - F.y * tt.y;   // (Fx+iFy)*(c + i s)
    im += F.x * tt.y + F.y * tt.x;
  }
  ((float2*)TY)[(bc * 128 + h) * 65 + wf] = make_float2(re, im);
}

// ---------------- K8: inverse real DFT along W (Hermitian), ortho 1/128 ------------
__global__ __launch_bounds__(128) void k8_irfft_rows(const float* __restrict__ TY,
                                                     float* __restrict__ out) {
  __shared__ float2 Z[65];
  __shared__ float2 tw[128];
  int tid = threadIdx.x;
  {
    float sv, cv;
    sincosf(PI2f * (float)tid * (1.f / 128.f), &sv, &cv);
    tw[tid] = make_float2(cv, sv);
  }
  int row = blockIdx.x;  // (b*C+c)*H + h
  if (tid < 65) Z[tid] = ((const float2*)TY)[row * 65 + tid];
  __syncthreads();
  int w = tid;
  float acc = Z[0].x + ((w & 1) ? -Z[64].x : Z[64].x);
  for (int k = 1; k < 64; k++) {
    float2 tt = tw[(k * w) & 127];
    acc += 2.f * (Z[k].x * tt.x - Z[k].y * tt.y);
  }
  out[row * 128 + w] = acc * (1.f / 128.f);
}

extern "C" void kernel_launch(void* const* d_in, const int* in_sizes, int n_in,
                              void* d_out, int out_size, void* d_ws, size_t ws_size,
                              hipStream_t stream) {
  const float* x      = (const float*)d_in[0];
  const float* h_prev = (const float*)d_in[1];
  const float* nw     = (const float*)d_in[2];
  const float* nb     = (const float*)d_in[3];
  const float* Wx     = (const float*)d_in[4];
  const float* Wb     = (const float*)d_in[5];
  const float* Wc     = (const float*)d_in[6];
  const float* wdt    = (const float*)d_in[7];
  const float* dtbias = (const float*)d_in[8];
  const float* Alog   = (const float*)d_in[9];
  const float* Dskip  = (const float*)d_in[10];
  const float* Wout   = (const float*)d_in[11];
  float* out = (float*)d_out;

  float* ws = (float*)d_ws;
  const size_t SZ_BIG = 4259840;  // B*L*D
  const size_t SZ_BN  = 2129920;  // B*L*N
  float* R1    = ws;              // T1 (rfft rows) then T2 (freq_out)
  float* R2    = R1 + SZ_BIG;     // u, then Sseg
  float* R3    = R2 + SZ_BIG;     // xs, then Hp
  float* R4    = R3 + SZ_BIG;     // ybuf, then TY (ifft-cols out)
  float* Bs    = R4 + SZ_BIG;
  float* Cs    = Bs + SZ_BN;
  float* dtb   = Cs + SZ_BN;      // 33280
  float* decb  = dtb + 33280;     // 33280 (unused now)
  float* cumg  = decb + 33280;    // 33280
  float* ssegb = cumg + 33280;    // 520
  float* WcatT = ssegb + 520;     // 32768
  float* WoT   = WcatT + 32768;   // 16384

  hipLaunchKernelGGL(k0_transpose, dim3(128), dim3(256), 0, stream, Wx, Wb, Wc, Wout, WcatT, WoT);
  hipLaunchKernelGGL(k1_rfft_rows, dim3(8192), dim3(256), 0, stream, x, R1);
  hipLaunchKernelGGL(k2_fft_cols, dim3(16640), dim3(128), 0, stream, R1, R2);
  hipLaunchKernelGGL(k3_ln_proj, dim3(1040), dim3(256), 0, stream,
                     R2, WcatT, nw, nb, wdt, dtbias, R3, Bs, Cs, dtb);
  hipLaunchKernelGGL(k5_seg, dim3(520), dim3(256), 0, stream,
                     R3, Bs, Cs, dtb, Alog, Dskip, R4, R2 /*Sseg*/, ssegb, cumg);
  hipLaunchKernelGGL(k5b_states, dim3(128), dim3(256), 0, stream,
                     h_prev, R2, ssegb, R3 /*Hp*/, out + 4194304);
  hipLaunchKernelGGL(k5c_correct, dim3(520), dim3(256), 0, stream, Cs, R3, cumg, R4);
  hipLaunchKernelGGL(k6_outproj, dim3(1040), dim3(256), 0, stream, R4, WoT, R1 /*T2*/);
  hipLaunchKernelGGL(k7_ifft_cols, dim3(16640), dim3(128), 0, stream, R1, R4 /*TY*/);
  hipLaunchKernelGGL(k8_irfft_rows, dim3(32768), dim3(128), 0, stream, R4, out);
}